// Round 9
// baseline (168.748 us; speedup 1.0000x reference)
//
#include <hip/hip_runtime.h>

#define BB 2
#define NN 16384
#define CC 64
#define SS 4096
#define KK 32
#define R2 0.16f   // RADIUS^2

typedef __bf16 bf16x8 __attribute__((ext_vector_type(8)));
typedef float  f32x4  __attribute__((ext_vector_type(4)));

#define MFMA(a, b, c) __builtin_amdgcn_mfma_f32_16x16x32_bf16((a), (b), (c), 0, 0, 0)

static __device__ __forceinline__ ushort f2bf(float f) {
    __bf16 h = (__bf16)f;
    return *(ushort*)&h;
}

// workspace section offsets (bytes)
#define WS_IDX    0          // idx_ws:  2*4096*32*4   = 1,048,576
#define WS_PTS4   1048576    // pts4:    2*16384*16    =   524,288
#define WS_FEAT   1572864    // feat_nc: 2*16384*64*2  = 4,194,304
#define WS_W1T    5767168    // 64*96*2   = 12,288
#define WS_W2T    5779456    // 64*64*2   =  8,192
#define WS_W3T    5787648    // 128*64*2  = 16,384

// prep index ranges (misc section, then feat-transpose section)
#define T_PTS   (BB * NN)                  // 32768
#define T_W1    (T_PTS + 64 * 96)          // 38912
#define T_W2    (T_W1 + 64 * 64)           // 43008
#define T_W3    (T_W2 + 128 * 64)          // 51200
#define T_NXYZ  (T_W3 + BB * SS * 3)       // 75776
#define T_SIDX  (T_NXYZ + BB * SS)         // 83968
#define T_ALL   (T_SIDX + BB * NN)         // 116736 (feat threads)

// ---------------------------------------------------------------------------
// prep: pts4=(x,y,z,|x|^2); bf16 weight transposes; coalesced new_xyz copy;
// samp_idx; feat [B][C][N] fp32 -> [B][N][C] bf16. One launch. (unchanged)
// ---------------------------------------------------------------------------
__global__ __launch_bounds__(256) void prep_kernel(
        const float* __restrict__ xyz, const float* __restrict__ feat,
        const float* __restrict__ W1, const float* __restrict__ W2,
        const float* __restrict__ W3,
        float4* __restrict__ pts4, ushort* __restrict__ feat_nc,
        ushort* __restrict__ W1t, ushort* __restrict__ W2t,
        ushort* __restrict__ W3t,
        float* __restrict__ out_xyz, float* __restrict__ out_sidx) {
    const int t = blockIdx.x * 256 + threadIdx.x;
    if (t < T_PTS) {
        const float* p = xyz + (size_t)t * 3;
        const float x = p[0], y = p[1], z = p[2];
        pts4[t] = make_float4(x, y, z, x * x + y * y + z * z);
    } else if (t < T_W1) {
        const int i = t - T_PTS;
        const int n = i / 96, k = i - n * 96;
        float v = 0.0f;
        if (k < 64) v = W1[(3 + k) * 64 + n];
        else if (k < 67) v = W1[(k - 64) * 64 + n];
        W1t[n * 96 + k] = f2bf(v);
    } else if (t < T_W2) {
        const int i = t - T_W1;
        const int n = i >> 6, k = i & 63;
        W2t[n * 64 + k] = f2bf(W2[k * 64 + n]);
    } else if (t < T_W3) {
        const int i = t - T_W2;
        const int n = i >> 6, k = i & 63;
        W3t[n * 64 + k] = f2bf(W3[k * 128 + n]);
    } else if (t < T_NXYZ) {
        const int i = t - T_W3;              // new_xyz = xyz[:, :SS] copy
        const int b = i / (SS * 3), j = i - b * (SS * 3);
        out_xyz[i] = xyz[(size_t)b * NN * 3 + j];
    } else if (t < T_SIDX) {
        const int i = t - T_NXYZ;
        out_sidx[i] = (float)(i & (SS - 1));
    } else if (t < T_ALL) {
        const int i = t - T_SIDX;            // 0 .. BB*NN-1
        const int b = i >> 14, n = i & (NN - 1);
        const float* fb = feat + (size_t)b * CC * NN + n;
        ushort* dst = feat_nc + (size_t)i * 64;
        #pragma unroll
        for (int c8 = 0; c8 < 8; ++c8) {
            uint u[4];
            #pragma unroll
            for (int j = 0; j < 4; ++j) {
                const float f0 = fb[(size_t)(c8 * 8 + 2 * j) * NN];
                const float f1 = fb[(size_t)(c8 * 8 + 2 * j + 1) * NN];
                u[j] = (uint)f2bf(f0) | ((uint)f2bf(f1) << 16);
            }
            *(uint4*)(dst + c8 * 8) = make_uint4(u[0], u[1], u[2], u[3]);
        }
    }
}

// ---------------------------------------------------------------------------
// bq: STATIC one wave per centroid; wave-uniform zero-hit guard; NEW: 2-deep
// chunk pipeline — while computing chunk k, loads for chunks k+1 AND k+2 are
// in flight (R8's 1-deep left ~150-220 cyc exposed L2 latency per chunk for
// the ~18% full-scan stragglers that dominate the tail at 1-2 waves/SIMD).
// ---------------------------------------------------------------------------
__global__ __launch_bounds__(256) void bq_kernel(const float4* __restrict__ pts4,
                                                 int* __restrict__ idx_ws) {
    const int w = threadIdx.x >> 6, lane = threadIdx.x & 63;
    const int sg = blockIdx.x * 4 + w;       // 0 .. BB*SS-1
    const int b = sg >> 12, s = sg & (SS - 1);

    __shared__ int hits[4][KK];
    int* hit = hits[w];
    const unsigned long long ltmask = (1ull << lane) - 1ull;

    const float4* pb = pts4 + (size_t)b * NN;
    const float4 c = pb[s];

    // prologue: chunk 0 -> P, chunk 1 -> Q
    float4 p0 = pb[lane],       p1 = pb[64 + lane];
    float4 p2 = pb[128 + lane], p3 = pb[192 + lane];
    float4 q0 = pb[256 + lane],       q1 = pb[256 + 64 + lane];
    float4 q2 = pb[256 + 128 + lane], q3 = pb[256 + 192 + lane];

    int cnt = 0;
    for (int base = 0;;) {
        const int n2 = base + 512;
        const int pf = (n2 < NN) ? n2 : 0;     // chunk k+2 (clamped; may be unused)
        const float4 r0 = pb[pf + lane],       r1 = pb[pf + 64 + lane];
        const float4 r2 = pb[pf + 128 + lane], r3 = pb[pf + 192 + lane];

        const float d0 = c.w + p0.w - 2.0f * (c.x * p0.x + c.y * p0.y + c.z * p0.z);
        const float d1 = c.w + p1.w - 2.0f * (c.x * p1.x + c.y * p1.y + c.z * p1.z);
        const float d2 = c.w + p2.w - 2.0f * (c.x * p2.x + c.y * p2.y + c.z * p2.z);
        const float d3 = c.w + p3.w - 2.0f * (c.x * p3.x + c.y * p3.y + c.z * p3.z);
        const bool h0 = d0 < R2, h1 = d1 < R2, h2 = d2 < R2, h3 = d3 < R2;
        const unsigned long long m0 = __ballot(h0), m1 = __ballot(h1);
        const unsigned long long m2 = __ballot(h2), m3 = __ballot(h3);
        if ((m0 | m1 | m2 | m3) != 0ull) {     // wave-uniform: skip when no hits
            const int c0 = __popcll(m0), c1 = __popcll(m1);
            const int c2 = __popcll(m2), c3 = __popcll(m3);
            if (h0) { const int p = cnt + __popcll(m0 & ltmask);                if (p < KK) hit[p] = base + lane; }
            if (h1) { const int p = cnt + c0 + __popcll(m1 & ltmask);           if (p < KK) hit[p] = base + 64 + lane; }
            if (h2) { const int p = cnt + c0 + c1 + __popcll(m2 & ltmask);      if (p < KK) hit[p] = base + 128 + lane; }
            if (h3) { const int p = cnt + c0 + c1 + c2 + __popcll(m3 & ltmask); if (p < KK) hit[p] = base + 192 + lane; }
            cnt += c0 + c1 + c2 + c3;
        }
        if (cnt >= KK || base + 256 >= NN) break;
        base += 256;
        p0 = q0; p1 = q1; p2 = q2; p3 = q3;    // rotate pipeline
        q0 = r0; q1 = r1; q2 = r2; q3 = r3;
    }
    if (lane < KK) {
        const int v = (cnt == 0) ? 0 : ((lane < cnt) ? hit[lane] : hit[0]);
        idx_ws[(size_t)sg * KK + lane] = v;
    }
}

// ---------------------------------------------------------------------------
// mlp: unchanged from R8 (spill-free slim structure, __launch_bounds__(256,2)).
// ---------------------------------------------------------------------------
__global__ __launch_bounds__(256, 2) void mlp_kernel(
        const float4* __restrict__ pts4, const ushort* __restrict__ feat_nc,
        const ushort* __restrict__ W1t, const ushort* __restrict__ W2t,
        const ushort* __restrict__ W3t,
        const float* __restrict__ b1, const float* __restrict__ b2,
        const float* __restrict__ b3,
        const int* __restrict__ idx_ws, float* __restrict__ out_feat) {
    const int w = threadIdx.x >> 6, lane = threadIdx.x & 63;
    const int quad = lane >> 4, mrow = lane & 15;
    const int m = lane & 31, half = lane >> 5;

    __shared__ __align__(16) ushort ldsA[4][32 * 104];   // g -> h1 -> h2 per wave
    __shared__ float stage[128][9];                      // [ch][8 s + pad]
    ushort* gbuf = ldsA[w];

    // block -> (batch, s-range); block owns 8 consecutive s
    const int xcd = blockIdx.x & 7;
    const int j = blockIdx.x >> 3;                 // 0..127
    const int b = xcd >> 2;
    const int sbase = (xcd & 3) * 1024 + j * 8;    // block's 8-s tile
    const float4* pbase = pts4 + (size_t)b * NN;
    const ushort* fbase = feat_nc + (size_t)b * NN * 64;

    #pragma unroll 1
    for (int gi = 0; gi < 2; ++gi) {
        const int s = sbase + w * 2 + gi;
        const int grp = b * SS + s;

        // ---- gather: idx -> rows -> LDS (+ rel_xyz, zero pad) --------------
        {
            const int sid = idx_ws[(size_t)grp * KK + m];
            const ushort* src = fbase + (size_t)sid * 64 + half * 32;
            ushort* dst = gbuf + m * 104 + half * 32;
            #pragma unroll
            for (int i = 0; i < 4; ++i)
                *(uint4*)(dst + i * 8) = *(const uint4*)(src + i * 8);
            if (half == 0) {
                const float4 p = pbase[sid];
                const float4 cc = pbase[s];
                bf16x8 rel = {(__bf16)(p.x - cc.x), (__bf16)(p.y - cc.y),
                              (__bf16)(p.z - cc.z), (__bf16)0.f,
                              (__bf16)0.f, (__bf16)0.f, (__bf16)0.f, (__bf16)0.f};
                *(bf16x8*)(gbuf + m * 104 + 64) = rel;
                *(uint4*)(gbuf + m * 104 + 88) = make_uint4(0, 0, 0, 0);
            } else {
                *(uint4*)(gbuf + m * 104 + 72) = make_uint4(0, 0, 0, 0);
                *(uint4*)(gbuf + m * 104 + 80) = make_uint4(0, 0, 0, 0);
            }
        }

        // ---- layer 1: [32x96]x[96x64], W1 streamed; h1 overwrites g --------
        {
            f32x4 acc[2][4];
            #pragma unroll
            for (int nt = 0; nt < 4; ++nt) {
                const float bv = b1[nt * 16 + mrow];
                acc[0][nt] = (f32x4){bv, bv, bv, bv};
                acc[1][nt] = acc[0][nt];
            }
            #pragma unroll
            for (int ks = 0; ks < 3; ++ks) {
                const bf16x8 a0 = *(const bf16x8*)(gbuf + mrow * 104 + ks * 32 + quad * 8);
                const bf16x8 a1 = *(const bf16x8*)(gbuf + (16 + mrow) * 104 + ks * 32 + quad * 8);
                #pragma unroll
                for (int nt = 0; nt < 4; ++nt) {
                    const bf16x8 wf = *(const bf16x8*)(W1t + (nt * 16 + mrow) * 96 + ks * 32 + quad * 8);
                    acc[0][nt] = MFMA(a0, wf, acc[0][nt]);
                    acc[1][nt] = MFMA(a1, wf, acc[1][nt]);
                }
            }
            #pragma unroll
            for (int mt = 0; mt < 2; ++mt)
                #pragma unroll
                for (int nt = 0; nt < 4; ++nt)
                    #pragma unroll
                    for (int r = 0; r < 4; ++r)
                        gbuf[(mt * 16 + quad * 4 + r) * 104 + nt * 16 + mrow] =
                            f2bf(fmaxf(acc[mt][nt][r], 0.0f));
        }

        // ---- layer 2: [32x64]x[64x64], W2 streamed; h2 overwrites h1 -------
        {
            f32x4 acc[2][4];
            #pragma unroll
            for (int nt = 0; nt < 4; ++nt) {
                const float bv = b2[nt * 16 + mrow];
                acc[0][nt] = (f32x4){bv, bv, bv, bv};
                acc[1][nt] = acc[0][nt];
            }
            #pragma unroll
            for (int ks = 0; ks < 2; ++ks) {
                const bf16x8 a0 = *(const bf16x8*)(gbuf + mrow * 104 + ks * 32 + quad * 8);
                const bf16x8 a1 = *(const bf16x8*)(gbuf + (16 + mrow) * 104 + ks * 32 + quad * 8);
                #pragma unroll
                for (int nt = 0; nt < 4; ++nt) {
                    const bf16x8 wf = *(const bf16x8*)(W2t + (nt * 16 + mrow) * 64 + ks * 32 + quad * 8);
                    acc[0][nt] = MFMA(a0, wf, acc[0][nt]);
                    acc[1][nt] = MFMA(a1, wf, acc[1][nt]);
                }
            }
            #pragma unroll
            for (int mt = 0; mt < 2; ++mt)
                #pragma unroll
                for (int nt = 0; nt < 4; ++nt)
                    #pragma unroll
                    for (int r = 0; r < 4; ++r)
                        gbuf[(mt * 16 + quad * 4 + r) * 104 + nt * 16 + mrow] =
                            f2bf(fmaxf(acc[mt][nt][r], 0.0f));
        }

        // ---- layer 3: [32x64]x[64x128] in two n-halves; fused maxpool ------
        const int sl = w * 2 + gi;             // slot within the block's 8 s
        #pragma unroll
        for (int nh = 0; nh < 2; ++nh) {
            f32x4 acc[2][4];
            #pragma unroll
            for (int ntl = 0; ntl < 4; ++ntl) {
                const float bv = b3[(nh * 4 + ntl) * 16 + mrow];
                acc[0][ntl] = (f32x4){bv, bv, bv, bv};
                acc[1][ntl] = acc[0][ntl];
            }
            #pragma unroll
            for (int ks = 0; ks < 2; ++ks) {
                const bf16x8 a0 = *(const bf16x8*)(gbuf + mrow * 104 + ks * 32 + quad * 8);
                const bf16x8 a1 = *(const bf16x8*)(gbuf + (16 + mrow) * 104 + ks * 32 + quad * 8);
                #pragma unroll
                for (int ntl = 0; ntl < 4; ++ntl) {
                    const bf16x8 wf = *(const bf16x8*)(
                        W3t + ((nh * 4 + ntl) * 16 + mrow) * 64 + ks * 32 + quad * 8);
                    acc[0][ntl] = MFMA(a0, wf, acc[0][ntl]);
                    acc[1][ntl] = MFMA(a1, wf, acc[1][ntl]);
                }
            }
            #pragma unroll
            for (int ntl = 0; ntl < 4; ++ntl) {
                const f32x4 v0 = acc[0][ntl], v1 = acc[1][ntl];
                float mx = fmaxf(fmaxf(v0[0], v0[1]), fmaxf(v0[2], v0[3]));
                mx = fmaxf(mx, fmaxf(fmaxf(v1[0], v1[1]), fmaxf(v1[2], v1[3])));
                mx = fmaxf(mx, __shfl_xor(mx, 16));
                mx = fmaxf(mx, __shfl_xor(mx, 32));
                mx = fmaxf(mx, 0.0f);
                if (quad == 0) stage[(nh * 4 + ntl) * 16 + mrow][sl] = mx;
            }
        }
    }
    __syncthreads();

    // ---- fused transpose epilogue: 128 ch x 8 s, float4 per thread ---------
    {
        const int ch = threadIdx.x >> 1;
        const int j4 = (threadIdx.x & 1) * 4;
        const float* srow = &stage[ch][j4];
        float* dst = out_feat + ((size_t)b * 128 + ch) * SS + sbase + j4;
        *(float4*)dst = make_float4(srow[0], srow[1], srow[2], srow[3]);
    }
}

// ---------------------------------------------------------------------------
extern "C" void kernel_launch(void* const* d_in, const int* in_sizes, int n_in,
                              void* d_out, int out_size, void* d_ws, size_t ws_size,
                              hipStream_t stream) {
    const float* xyz  = (const float*)d_in[0];
    const float* feat = (const float*)d_in[1];
    const float* W1   = (const float*)d_in[2];
    const float* b1   = (const float*)d_in[3];
    const float* W2   = (const float*)d_in[4];
    const float* b2   = (const float*)d_in[5];
    const float* W3   = (const float*)d_in[6];
    const float* b3   = (const float*)d_in[7];

    float* out      = (float*)d_out;
    float* out_xyz  = out;                               // [2,4096,3]
    float* out_feat = out + (size_t)BB * SS * 3;         // [2,128,4096]
    float* out_sidx = out_feat + (size_t)BB * 128 * SS;  // [2,4096]

    char* ws = (char*)d_ws;
    int*    idx_ws  = (int*)(ws + WS_IDX);
    float4* pts4    = (float4*)(ws + WS_PTS4);
    ushort* feat_nc = (ushort*)(ws + WS_FEAT);
    ushort* W1t     = (ushort*)(ws + WS_W1T);
    ushort* W2t     = (ushort*)(ws + WS_W2T);
    ushort* W3t     = (ushort*)(ws + WS_W3T);

    prep_kernel<<<(T_ALL + 255) / 256, 256, 0, stream>>>(
        xyz, feat, W1, W2, W3, pts4, feat_nc, W1t, W2t, W3t, out_xyz, out_sidx);
    bq_kernel<<<BB * SS / 4, 256, 0, stream>>>(pts4, idx_ws);
    mlp_kernel<<<BB * SS / 8, 256, 0, stream>>>(pts4, feat_nc, W1t, W2t, W3t,
                                                b1, b2, b3, idx_ws, out_feat);
}

// Round 10
// 164.266 us; speedup vs baseline: 1.0273x; 1.0273x over previous
//
#include <hip/hip_runtime.h>

#define BB 2
#define NN 16384
#define CC 64
#define SS 4096
#define KK 32
#define R2 0.16f   // RADIUS^2

typedef __bf16 bf16x8 __attribute__((ext_vector_type(8)));
typedef float  f32x4  __attribute__((ext_vector_type(4)));

#define MFMA(a, b, c) __builtin_amdgcn_mfma_f32_16x16x32_bf16((a), (b), (c), 0, 0, 0)

static __device__ __forceinline__ ushort f2bf(float f) {
    __bf16 h = (__bf16)f;
    return *(ushort*)&h;
}

// workspace section offsets (bytes)
#define WS_IDX    0          // idx_ws:  2*4096*32*4   = 1,048,576
#define WS_PTS4   1048576    // pts4:    2*16384*16    =   524,288
#define WS_FEAT   1572864    // feat_nc: 2*16384*64*2  = 4,194,304
#define WS_W1T    5767168    // 64*96*2   = 12,288
#define WS_W2T    5779456    // 64*64*2   =  8,192
#define WS_W3T    5787648    // 128*64*2  = 16,384

// prep index ranges (misc section, then feat-transpose section)
#define T_PTS   (BB * NN)                  // 32768
#define T_W1    (T_PTS + 64 * 96)          // 38912
#define T_W2    (T_W1 + 64 * 64)           // 43008
#define T_W3    (T_W2 + 128 * 64)          // 51200
#define T_NXYZ  (T_W3 + BB * SS * 3)       // 75776
#define T_SIDX  (T_NXYZ + BB * SS)         // 83968
#define T_ALL   (T_SIDX + BB * NN)         // 116736 (feat threads)

// ---------------------------------------------------------------------------
// prep: pts4=(x,y,z,|x|^2); bf16 weight transposes; coalesced new_xyz copy;
// samp_idx; feat [B][C][N] fp32 -> [B][N][C] bf16. One launch. (unchanged)
// ---------------------------------------------------------------------------
__global__ __launch_bounds__(256) void prep_kernel(
        const float* __restrict__ xyz, const float* __restrict__ feat,
        const float* __restrict__ W1, const float* __restrict__ W2,
        const float* __restrict__ W3,
        float4* __restrict__ pts4, ushort* __restrict__ feat_nc,
        ushort* __restrict__ W1t, ushort* __restrict__ W2t,
        ushort* __restrict__ W3t,
        float* __restrict__ out_xyz, float* __restrict__ out_sidx) {
    const int t = blockIdx.x * 256 + threadIdx.x;
    if (t < T_PTS) {
        const float* p = xyz + (size_t)t * 3;
        const float x = p[0], y = p[1], z = p[2];
        pts4[t] = make_float4(x, y, z, x * x + y * y + z * z);
    } else if (t < T_W1) {
        const int i = t - T_PTS;
        const int n = i / 96, k = i - n * 96;
        float v = 0.0f;
        if (k < 64) v = W1[(3 + k) * 64 + n];
        else if (k < 67) v = W1[(k - 64) * 64 + n];
        W1t[n * 96 + k] = f2bf(v);
    } else if (t < T_W2) {
        const int i = t - T_W1;
        const int n = i >> 6, k = i & 63;
        W2t[n * 64 + k] = f2bf(W2[k * 64 + n]);
    } else if (t < T_W3) {
        const int i = t - T_W2;
        const int n = i >> 6, k = i & 63;
        W3t[n * 64 + k] = f2bf(W3[k * 128 + n]);
    } else if (t < T_NXYZ) {
        const int i = t - T_W3;              // new_xyz = xyz[:, :SS] copy
        const int b = i / (SS * 3), j = i - b * (SS * 3);
        out_xyz[i] = xyz[(size_t)b * NN * 3 + j];
    } else if (t < T_SIDX) {
        const int i = t - T_NXYZ;
        out_sidx[i] = (float)(i & (SS - 1));
    } else if (t < T_ALL) {
        const int i = t - T_SIDX;            // 0 .. BB*NN-1
        const int b = i >> 14, n = i & (NN - 1);
        const float* fb = feat + (size_t)b * CC * NN + n;
        ushort* dst = feat_nc + (size_t)i * 64;
        #pragma unroll
        for (int c8 = 0; c8 < 8; ++c8) {
            uint u[4];
            #pragma unroll
            for (int j = 0; j < 4; ++j) {
                const float f0 = fb[(size_t)(c8 * 8 + 2 * j) * NN];
                const float f1 = fb[(size_t)(c8 * 8 + 2 * j + 1) * NN];
                u[j] = (uint)f2bf(f0) | ((uint)f2bf(f1) << 16);
            }
            *(uint4*)(dst + c8 * 8) = make_uint4(u[0], u[1], u[2], u[3]);
        }
    }
}

// ---------------------------------------------------------------------------
// bq v10: ONE WAVE SCANS FOR 4 CENTROIDS (shared point stream). R9's
// arithmetic: 8192 independent waves re-streamed the same 256KB pts array
// -> ~680 MB of redundant L2 reads + 245K wave-iterations. Sharing the
// stream 4-ways cuts L2 traffic ~3x and iterations ~2.7x (scan = max over
// the 4, ~45 chunks avg); per-centroid scalar cnt<32 guard keeps exact
// first-32 semantics (skipped chunks only ever contain discarded hits).
// 1-deep prefetch (R8's proven depth; R9's 2-deep was compiler-demoted).
// ---------------------------------------------------------------------------
__global__ __launch_bounds__(256) void bq_kernel(const float4* __restrict__ pts4,
                                                 int* __restrict__ idx_ws) {
    const int w = threadIdx.x >> 6, lane = threadIdx.x & 63;
    const int wid = blockIdx.x * 4 + w;      // 0 .. 2047
    const int sg0 = wid * 4;                 // first of 4 centroids
    const int b = sg0 >> 12;
    const int s0 = sg0 & (SS - 1);

    __shared__ int hits[4][4 * KK];          // [wave][centroid][KK]
    int* hit = hits[w];
    const unsigned long long ltmask = (1ull << lane) - 1ull;

    const float4* pb = pts4 + (size_t)b * NN;
    const float4 c0 = pb[s0], c1 = pb[s0 + 1], c2 = pb[s0 + 2], c3 = pb[s0 + 3];

    int cnt0 = 0, cnt1 = 0, cnt2 = 0, cnt3 = 0;

    float4 p0 = pb[lane], p1 = pb[64 + lane];
    float4 p2 = pb[128 + lane], p3 = pb[192 + lane];
    for (int base = 0;;) {
        const int nb = base + 256;
        const bool last = nb >= NN;
        const int pf = last ? 0 : nb;
        // prefetch next chunk (independent of this chunk's ballots/break)
        const float4 q0 = pb[pf + lane], q1 = pb[pf + 64 + lane];
        const float4 q2 = pb[pf + 128 + lane], q3 = pb[pf + 192 + lane];

        #pragma unroll
        for (int j = 0; j < 4; ++j) {
            const int cj = (j == 0) ? cnt0 : (j == 1) ? cnt1 : (j == 2) ? cnt2 : cnt3;
            if (cj < KK) {                  // wave-uniform: skip done centroids
                const float4 c = (j == 0) ? c0 : (j == 1) ? c1 : (j == 2) ? c2 : c3;
                const float d0 = c.w + p0.w - 2.0f * (c.x * p0.x + c.y * p0.y + c.z * p0.z);
                const float d1 = c.w + p1.w - 2.0f * (c.x * p1.x + c.y * p1.y + c.z * p1.z);
                const float d2 = c.w + p2.w - 2.0f * (c.x * p2.x + c.y * p2.y + c.z * p2.z);
                const float d3 = c.w + p3.w - 2.0f * (c.x * p3.x + c.y * p3.y + c.z * p3.z);
                const bool h0 = d0 < R2, h1 = d1 < R2, h2 = d2 < R2, h3 = d3 < R2;
                const unsigned long long m0 = __ballot(h0), m1 = __ballot(h1);
                const unsigned long long m2 = __ballot(h2), m3 = __ballot(h3);
                if ((m0 | m1 | m2 | m3) != 0ull) {   // zero-hit guard
                    int cn = cj;
                    const int c0n = __popcll(m0), c1n = __popcll(m1);
                    const int c2n = __popcll(m2), c3n = __popcll(m3);
                    int* hj = hit + j * KK;
                    if (h0) { const int p = cn + __popcll(m0 & ltmask);                   if (p < KK) hj[p] = base + lane; }
                    if (h1) { const int p = cn + c0n + __popcll(m1 & ltmask);             if (p < KK) hj[p] = base + 64 + lane; }
                    if (h2) { const int p = cn + c0n + c1n + __popcll(m2 & ltmask);       if (p < KK) hj[p] = base + 128 + lane; }
                    if (h3) { const int p = cn + c0n + c1n + c2n + __popcll(m3 & ltmask); if (p < KK) hj[p] = base + 192 + lane; }
                    cn += c0n + c1n + c2n + c3n;
                    if (j == 0) cnt0 = cn; else if (j == 1) cnt1 = cn;
                    else if (j == 2) cnt2 = cn; else cnt3 = cn;
                }
            }
        }
        if ((cnt0 >= KK && cnt1 >= KK && cnt2 >= KK && cnt3 >= KK) || last) break;
        base = nb;
        p0 = q0; p1 = q1; p2 = q2; p3 = q3;
    }

    // epilogue: 4 centroids, lanes 0..31 each
    #pragma unroll
    for (int j = 0; j < 4; ++j) {
        const int cj = (j == 0) ? cnt0 : (j == 1) ? cnt1 : (j == 2) ? cnt2 : cnt3;
        if (lane < KK) {
            const int* hj = hit + j * KK;
            const int v = (cj == 0) ? 0 : ((lane < cj) ? hj[lane] : hj[0]);
            idx_ws[(size_t)(sg0 + j) * KK + lane] = v;
        }
    }
}

// ---------------------------------------------------------------------------
// mlp: unchanged from R8 (spill-free slim structure, __launch_bounds__(256,2)).
// ---------------------------------------------------------------------------
__global__ __launch_bounds__(256, 2) void mlp_kernel(
        const float4* __restrict__ pts4, const ushort* __restrict__ feat_nc,
        const ushort* __restrict__ W1t, const ushort* __restrict__ W2t,
        const ushort* __restrict__ W3t,
        const float* __restrict__ b1, const float* __restrict__ b2,
        const float* __restrict__ b3,
        const int* __restrict__ idx_ws, float* __restrict__ out_feat) {
    const int w = threadIdx.x >> 6, lane = threadIdx.x & 63;
    const int quad = lane >> 4, mrow = lane & 15;
    const int m = lane & 31, half = lane >> 5;

    __shared__ __align__(16) ushort ldsA[4][32 * 104];   // g -> h1 -> h2 per wave
    __shared__ float stage[128][9];                      // [ch][8 s + pad]
    ushort* gbuf = ldsA[w];

    // block -> (batch, s-range); block owns 8 consecutive s
    const int xcd = blockIdx.x & 7;
    const int j = blockIdx.x >> 3;                 // 0..127
    const int b = xcd >> 2;
    const int sbase = (xcd & 3) * 1024 + j * 8;    // block's 8-s tile
    const float4* pbase = pts4 + (size_t)b * NN;
    const ushort* fbase = feat_nc + (size_t)b * NN * 64;

    #pragma unroll 1
    for (int gi = 0; gi < 2; ++gi) {
        const int s = sbase + w * 2 + gi;
        const int grp = b * SS + s;

        // ---- gather: idx -> rows -> LDS (+ rel_xyz, zero pad) --------------
        {
            const int sid = idx_ws[(size_t)grp * KK + m];
            const ushort* src = fbase + (size_t)sid * 64 + half * 32;
            ushort* dst = gbuf + m * 104 + half * 32;
            #pragma unroll
            for (int i = 0; i < 4; ++i)
                *(uint4*)(dst + i * 8) = *(const uint4*)(src + i * 8);
            if (half == 0) {
                const float4 p = pbase[sid];
                const float4 cc = pbase[s];
                bf16x8 rel = {(__bf16)(p.x - cc.x), (__bf16)(p.y - cc.y),
                              (__bf16)(p.z - cc.z), (__bf16)0.f,
                              (__bf16)0.f, (__bf16)0.f, (__bf16)0.f, (__bf16)0.f};
                *(bf16x8*)(gbuf + m * 104 + 64) = rel;
                *(uint4*)(gbuf + m * 104 + 88) = make_uint4(0, 0, 0, 0);
            } else {
                *(uint4*)(gbuf + m * 104 + 72) = make_uint4(0, 0, 0, 0);
                *(uint4*)(gbuf + m * 104 + 80) = make_uint4(0, 0, 0, 0);
            }
        }

        // ---- layer 1: [32x96]x[96x64], W1 streamed; h1 overwrites g --------
        {
            f32x4 acc[2][4];
            #pragma unroll
            for (int nt = 0; nt < 4; ++nt) {
                const float bv = b1[nt * 16 + mrow];
                acc[0][nt] = (f32x4){bv, bv, bv, bv};
                acc[1][nt] = acc[0][nt];
            }
            #pragma unroll
            for (int ks = 0; ks < 3; ++ks) {
                const bf16x8 a0 = *(const bf16x8*)(gbuf + mrow * 104 + ks * 32 + quad * 8);
                const bf16x8 a1 = *(const bf16x8*)(gbuf + (16 + mrow) * 104 + ks * 32 + quad * 8);
                #pragma unroll
                for (int nt = 0; nt < 4; ++nt) {
                    const bf16x8 wf = *(const bf16x8*)(W1t + (nt * 16 + mrow) * 96 + ks * 32 + quad * 8);
                    acc[0][nt] = MFMA(a0, wf, acc[0][nt]);
                    acc[1][nt] = MFMA(a1, wf, acc[1][nt]);
                }
            }
            #pragma unroll
            for (int mt = 0; mt < 2; ++mt)
                #pragma unroll
                for (int nt = 0; nt < 4; ++nt)
                    #pragma unroll
                    for (int r = 0; r < 4; ++r)
                        gbuf[(mt * 16 + quad * 4 + r) * 104 + nt * 16 + mrow] =
                            f2bf(fmaxf(acc[mt][nt][r], 0.0f));
        }

        // ---- layer 2: [32x64]x[64x64], W2 streamed; h2 overwrites h1 -------
        {
            f32x4 acc[2][4];
            #pragma unroll
            for (int nt = 0; nt < 4; ++nt) {
                const float bv = b2[nt * 16 + mrow];
                acc[0][nt] = (f32x4){bv, bv, bv, bv};
                acc[1][nt] = acc[0][nt];
            }
            #pragma unroll
            for (int ks = 0; ks < 2; ++ks) {
                const bf16x8 a0 = *(const bf16x8*)(gbuf + mrow * 104 + ks * 32 + quad * 8);
                const bf16x8 a1 = *(const bf16x8*)(gbuf + (16 + mrow) * 104 + ks * 32 + quad * 8);
                #pragma unroll
                for (int nt = 0; nt < 4; ++nt) {
                    const bf16x8 wf = *(const bf16x8*)(W2t + (nt * 16 + mrow) * 64 + ks * 32 + quad * 8);
                    acc[0][nt] = MFMA(a0, wf, acc[0][nt]);
                    acc[1][nt] = MFMA(a1, wf, acc[1][nt]);
                }
            }
            #pragma unroll
            for (int mt = 0; mt < 2; ++mt)
                #pragma unroll
                for (int nt = 0; nt < 4; ++nt)
                    #pragma unroll
                    for (int r = 0; r < 4; ++r)
                        gbuf[(mt * 16 + quad * 4 + r) * 104 + nt * 16 + mrow] =
                            f2bf(fmaxf(acc[mt][nt][r], 0.0f));
        }

        // ---- layer 3: [32x64]x[64x128] in two n-halves; fused maxpool ------
        const int sl = w * 2 + gi;             // slot within the block's 8 s
        #pragma unroll
        for (int nh = 0; nh < 2; ++nh) {
            f32x4 acc[2][4];
            #pragma unroll
            for (int ntl = 0; ntl < 4; ++ntl) {
                const float bv = b3[(nh * 4 + ntl) * 16 + mrow];
                acc[0][ntl] = (f32x4){bv, bv, bv, bv};
                acc[1][ntl] = acc[0][ntl];
            }
            #pragma unroll
            for (int ks = 0; ks < 2; ++ks) {
                const bf16x8 a0 = *(const bf16x8*)(gbuf + mrow * 104 + ks * 32 + quad * 8);
                const bf16x8 a1 = *(const bf16x8*)(gbuf + (16 + mrow) * 104 + ks * 32 + quad * 8);
                #pragma unroll
                for (int ntl = 0; ntl < 4; ++ntl) {
                    const bf16x8 wf = *(const bf16x8*)(
                        W3t + ((nh * 4 + ntl) * 16 + mrow) * 64 + ks * 32 + quad * 8);
                    acc[0][ntl] = MFMA(a0, wf, acc[0][ntl]);
                    acc[1][ntl] = MFMA(a1, wf, acc[1][ntl]);
                }
            }
            #pragma unroll
            for (int ntl = 0; ntl < 4; ++ntl) {
                const f32x4 v0 = acc[0][ntl], v1 = acc[1][ntl];
                float mx = fmaxf(fmaxf(v0[0], v0[1]), fmaxf(v0[2], v0[3]));
                mx = fmaxf(mx, fmaxf(fmaxf(v1[0], v1[1]), fmaxf(v1[2], v1[3])));
                mx = fmaxf(mx, __shfl_xor(mx, 16));
                mx = fmaxf(mx, __shfl_xor(mx, 32));
                mx = fmaxf(mx, 0.0f);
                if (quad == 0) stage[(nh * 4 + ntl) * 16 + mrow][sl] = mx;
            }
        }
    }
    __syncthreads();

    // ---- fused transpose epilogue: 128 ch x 8 s, float4 per thread ---------
    {
        const int ch = threadIdx.x >> 1;
        const int j4 = (threadIdx.x & 1) * 4;
        const float* srow = &stage[ch][j4];
        float* dst = out_feat + ((size_t)b * 128 + ch) * SS + sbase + j4;
        *(float4*)dst = make_float4(srow[0], srow[1], srow[2], srow[3]);
    }
}

// ---------------------------------------------------------------------------
extern "C" void kernel_launch(void* const* d_in, const int* in_sizes, int n_in,
                              void* d_out, int out_size, void* d_ws, size_t ws_size,
                              hipStream_t stream) {
    const float* xyz  = (const float*)d_in[0];
    const float* feat = (const float*)d_in[1];
    const float* W1   = (const float*)d_in[2];
    const float* b1   = (const float*)d_in[3];
    const float* W2   = (const float*)d_in[4];
    const float* b2   = (const float*)d_in[5];
    const float* W3   = (const float*)d_in[6];
    const float* b3   = (const float*)d_in[7];

    float* out      = (float*)d_out;
    float* out_xyz  = out;                               // [2,4096,3]
    float* out_feat = out + (size_t)BB * SS * 3;         // [2,128,4096]
    float* out_sidx = out_feat + (size_t)BB * 128 * SS;  // [2,4096]

    char* ws = (char*)d_ws;
    int*    idx_ws  = (int*)(ws + WS_IDX);
    float4* pts4    = (float4*)(ws + WS_PTS4);
    ushort* feat_nc = (ushort*)(ws + WS_FEAT);
    ushort* W1t     = (ushort*)(ws + WS_W1T);
    ushort* W2t     = (ushort*)(ws + WS_W2T);
    ushort* W3t     = (ushort*)(ws + WS_W3T);

    prep_kernel<<<(T_ALL + 255) / 256, 256, 0, stream>>>(
        xyz, feat, W1, W2, W3, pts4, feat_nc, W1t, W2t, W3t, out_xyz, out_sidx);
    bq_kernel<<<BB * SS / 16, 256, 0, stream>>>(pts4, idx_ws);
    mlp_kernel<<<BB * SS / 8, 256, 0, stream>>>(pts4, feat_nc, W1t, W2t, W3t,
                                                b1, b2, b3, idx_ws, out_feat);
}

// Round 11
// 155.699 us; speedup vs baseline: 1.0838x; 1.0550x over previous
//
#include <hip/hip_runtime.h>

#define BB 2
#define NN 16384
#define CC 64
#define SS 4096
#define KK 32
#define R2 0.16f   // RADIUS^2

typedef __bf16 bf16x8 __attribute__((ext_vector_type(8)));
typedef float  f32x4  __attribute__((ext_vector_type(4)));

#define MFMA(a, b, c) __builtin_amdgcn_mfma_f32_16x16x32_bf16((a), (b), (c), 0, 0, 0)

static __device__ __forceinline__ ushort f2bf(float f) {
    __bf16 h = (__bf16)f;
    return *(ushort*)&h;
}

// workspace section offsets (bytes)
#define WS_PTS4   0          // pts4:    2*16384*16    =   524,288
#define WS_FEAT   524288     // feat_nc: 2*16384*64*2  = 4,194,304
#define WS_W1T    4718592    // 64*96*2   = 12,288
#define WS_W2T    4730880    // 64*64*2   =  8,192
#define WS_W3T    4739072    // 128*64*2  = 16,384

// prep index ranges
#define T_PTS   (BB * NN)                  // 32768
#define T_W1    (T_PTS + 64 * 96)          // 38912
#define T_W2    (T_W1 + 64 * 64)           // 43008
#define T_W3    (T_W2 + 128 * 64)          // 51200
#define T_NXYZ  (T_W3 + BB * SS * 3)       // 75776
#define T_SIDX  (T_NXYZ + BB * SS)         // 83968
#define T_ALL   (T_SIDX + BB * NN)         // 116736 (feat threads)

// ---------------------------------------------------------------------------
// prep: pts4=(x,y,z,|x|^2); bf16 weight transposes; coalesced new_xyz copy;
// samp_idx; feat [B][C][N] fp32 -> [B][N][C] bf16. One launch. (unchanged)
// ---------------------------------------------------------------------------
__global__ __launch_bounds__(256) void prep_kernel(
        const float* __restrict__ xyz, const float* __restrict__ feat,
        const float* __restrict__ W1, const float* __restrict__ W2,
        const float* __restrict__ W3,
        float4* __restrict__ pts4, ushort* __restrict__ feat_nc,
        ushort* __restrict__ W1t, ushort* __restrict__ W2t,
        ushort* __restrict__ W3t,
        float* __restrict__ out_xyz, float* __restrict__ out_sidx) {
    const int t = blockIdx.x * 256 + threadIdx.x;
    if (t < T_PTS) {
        const float* p = xyz + (size_t)t * 3;
        const float x = p[0], y = p[1], z = p[2];
        pts4[t] = make_float4(x, y, z, x * x + y * y + z * z);
    } else if (t < T_W1) {
        const int i = t - T_PTS;
        const int n = i / 96, k = i - n * 96;
        float v = 0.0f;
        if (k < 64) v = W1[(3 + k) * 64 + n];
        else if (k < 67) v = W1[(k - 64) * 64 + n];
        W1t[n * 96 + k] = f2bf(v);
    } else if (t < T_W2) {
        const int i = t - T_W1;
        const int n = i >> 6, k = i & 63;
        W2t[n * 64 + k] = f2bf(W2[k * 64 + n]);
    } else if (t < T_W3) {
        const int i = t - T_W2;
        const int n = i >> 6, k = i & 63;
        W3t[n * 64 + k] = f2bf(W3[k * 128 + n]);
    } else if (t < T_NXYZ) {
        const int i = t - T_W3;              // new_xyz = xyz[:, :SS] copy
        const int b = i / (SS * 3), j = i - b * (SS * 3);
        out_xyz[i] = xyz[(size_t)b * NN * 3 + j];
    } else if (t < T_SIDX) {
        const int i = t - T_NXYZ;
        out_sidx[i] = (float)(i & (SS - 1));
    } else if (t < T_ALL) {
        const int i = t - T_SIDX;            // 0 .. BB*NN-1
        const int b = i >> 14, n = i & (NN - 1);
        const float* fb = feat + (size_t)b * CC * NN + n;
        ushort* dst = feat_nc + (size_t)i * 64;
        #pragma unroll
        for (int c8 = 0; c8 < 8; ++c8) {
            uint u[4];
            #pragma unroll
            for (int j = 0; j < 4; ++j) {
                const float f0 = fb[(size_t)(c8 * 8 + 2 * j) * NN];
                const float f1 = fb[(size_t)(c8 * 8 + 2 * j + 1) * NN];
                u[j] = (uint)f2bf(f0) | ((uint)f2bf(f1) << 16);
            }
            *(uint4*)(dst + c8 * 8) = make_uint4(u[0], u[1], u[2], u[3]);
        }
    }
}

// ---------------------------------------------------------------------------
// fused: one wave = one centroid: ball-query (R8's proven scan, hit list in
// the wave's private LDS region) -> immediately that group's MLP. No global
// idx round-trip, no barrier between a wave's bq and its mlp — early waves'
// MFMA work fills the issue slots the bq straggler tail leaves idle.
// Block = 4 waves = 4 consecutive s; tiny staged fp32 epilogue after one
// __syncthreads. 2048 blocks; XCD swizzle maps xcd 0-3 -> batch 0, 4-7 -> 1.
// ---------------------------------------------------------------------------
__global__ __launch_bounds__(256, 2) void fused_kernel(
        const float4* __restrict__ pts4, const ushort* __restrict__ feat_nc,
        const ushort* __restrict__ W1t, const ushort* __restrict__ W2t,
        const ushort* __restrict__ W3t,
        const float* __restrict__ b1, const float* __restrict__ b2,
        const float* __restrict__ b3, float* __restrict__ out_feat) {
    const int w = threadIdx.x >> 6, lane = threadIdx.x & 63;
    const int quad = lane >> 4, mrow = lane & 15;
    const int m = lane & 31, half = lane >> 5;

    __shared__ __align__(16) ushort ldsA[4][32 * 104];   // hits -> g -> h1 -> h2
    __shared__ float stage[128][5];                      // [ch][4 s + pad]
    ushort* gbuf = ldsA[w];
    int* hit = (int*)gbuf;                               // 128B bq scratch

    const int xcd = blockIdx.x & 7;
    const int slot = blockIdx.x >> 3;              // 0..255
    const int b = xcd >> 2;
    const int s0 = ((xcd & 3) * 256 + slot) * 4;   // block's 4-s tile
    const int s = s0 + w;

    const float4* pb = pts4 + (size_t)b * NN;
    const ushort* fbase = feat_nc + (size_t)b * NN * 64;
    const unsigned long long ltmask = (1ull << lane) - 1ull;

    // ================= ball query (R8 structure) =================
    {
        const float4 c = pb[s];
        float4 p0 = pb[lane], p1 = pb[64 + lane];
        float4 p2 = pb[128 + lane], p3 = pb[192 + lane];
        int cnt = 0;
        for (int base = 0;;) {
            const int nb = base + 256;
            const bool last = nb >= NN;
            const int pf = last ? 0 : nb;
            const float4 q0 = pb[pf + lane], q1 = pb[pf + 64 + lane];
            const float4 q2 = pb[pf + 128 + lane], q3 = pb[pf + 192 + lane];

            const float d0 = c.w + p0.w - 2.0f * (c.x * p0.x + c.y * p0.y + c.z * p0.z);
            const float d1 = c.w + p1.w - 2.0f * (c.x * p1.x + c.y * p1.y + c.z * p1.z);
            const float d2 = c.w + p2.w - 2.0f * (c.x * p2.x + c.y * p2.y + c.z * p2.z);
            const float d3 = c.w + p3.w - 2.0f * (c.x * p3.x + c.y * p3.y + c.z * p3.z);
            const bool h0 = d0 < R2, h1 = d1 < R2, h2 = d2 < R2, h3 = d3 < R2;
            const unsigned long long m0 = __ballot(h0), m1 = __ballot(h1);
            const unsigned long long m2 = __ballot(h2), m3 = __ballot(h3);
            if ((m0 | m1 | m2 | m3) != 0ull) {   // wave-uniform zero-hit guard
                const int c0 = __popcll(m0), c1 = __popcll(m1);
                const int c2 = __popcll(m2), c3 = __popcll(m3);
                if (h0) { const int p = cnt + __popcll(m0 & ltmask);                if (p < KK) hit[p] = base + lane; }
                if (h1) { const int p = cnt + c0 + __popcll(m1 & ltmask);           if (p < KK) hit[p] = base + 64 + lane; }
                if (h2) { const int p = cnt + c0 + c1 + __popcll(m2 & ltmask);      if (p < KK) hit[p] = base + 128 + lane; }
                if (h3) { const int p = cnt + c0 + c1 + c2 + __popcll(m3 & ltmask); if (p < KK) hit[p] = base + 192 + lane; }
                cnt += c0 + c1 + c2 + c3;
            }
            if (cnt >= KK || last) break;
            base = nb;
            p0 = q0; p1 = q1; p2 = q2; p3 = q3;
        }
        // finalize sid list in place (reads drain before the write issues)
        if (lane < KK) {
            const int v = (cnt == 0) ? 0 : ((lane < cnt) ? hit[lane] : hit[0]);
            hit[lane] = v;
        }
    }

    // ================= gather: sid (LDS) -> rows -> LDS =================
    {
        const int sid = hit[m];                  // wave-private, program order
        const ushort* src = fbase + (size_t)sid * 64 + half * 32;
        ushort* dst = gbuf + m * 104 + half * 32;
        uint4 rows[4];
        #pragma unroll
        for (int i = 0; i < 4; ++i) rows[i] = *(const uint4*)(src + i * 8);
        const float4 p = pb[sid];
        const float4 cc = pb[s];
        #pragma unroll
        for (int i = 0; i < 4; ++i) *(uint4*)(dst + i * 8) = rows[i];
        if (half == 0) {
            bf16x8 rel = {(__bf16)(p.x - cc.x), (__bf16)(p.y - cc.y),
                          (__bf16)(p.z - cc.z), (__bf16)0.f,
                          (__bf16)0.f, (__bf16)0.f, (__bf16)0.f, (__bf16)0.f};
            *(bf16x8*)(gbuf + m * 104 + 64) = rel;
            *(uint4*)(gbuf + m * 104 + 88) = make_uint4(0, 0, 0, 0);
        } else {
            *(uint4*)(gbuf + m * 104 + 72) = make_uint4(0, 0, 0, 0);
            *(uint4*)(gbuf + m * 104 + 80) = make_uint4(0, 0, 0, 0);
        }
    }

    // ================= layer 1: [32x96]x[96x64] =================
    {
        f32x4 acc[2][4];
        #pragma unroll
        for (int nt = 0; nt < 4; ++nt) {
            const float bv = b1[nt * 16 + mrow];
            acc[0][nt] = (f32x4){bv, bv, bv, bv};
            acc[1][nt] = acc[0][nt];
        }
        #pragma unroll
        for (int ks = 0; ks < 3; ++ks) {
            const bf16x8 a0 = *(const bf16x8*)(gbuf + mrow * 104 + ks * 32 + quad * 8);
            const bf16x8 a1 = *(const bf16x8*)(gbuf + (16 + mrow) * 104 + ks * 32 + quad * 8);
            #pragma unroll
            for (int nt = 0; nt < 4; ++nt) {
                const bf16x8 wf = *(const bf16x8*)(W1t + (nt * 16 + mrow) * 96 + ks * 32 + quad * 8);
                acc[0][nt] = MFMA(a0, wf, acc[0][nt]);
                acc[1][nt] = MFMA(a1, wf, acc[1][nt]);
            }
        }
        #pragma unroll
        for (int mt = 0; mt < 2; ++mt)
            #pragma unroll
            for (int nt = 0; nt < 4; ++nt)
                #pragma unroll
                for (int r = 0; r < 4; ++r)
                    gbuf[(mt * 16 + quad * 4 + r) * 104 + nt * 16 + mrow] =
                        f2bf(fmaxf(acc[mt][nt][r], 0.0f));
    }

    // ================= layer 2: [32x64]x[64x64] =================
    {
        f32x4 acc[2][4];
        #pragma unroll
        for (int nt = 0; nt < 4; ++nt) {
            const float bv = b2[nt * 16 + mrow];
            acc[0][nt] = (f32x4){bv, bv, bv, bv};
            acc[1][nt] = acc[0][nt];
        }
        #pragma unroll
        for (int ks = 0; ks < 2; ++ks) {
            const bf16x8 a0 = *(const bf16x8*)(gbuf + mrow * 104 + ks * 32 + quad * 8);
            const bf16x8 a1 = *(const bf16x8*)(gbuf + (16 + mrow) * 104 + ks * 32 + quad * 8);
            #pragma unroll
            for (int nt = 0; nt < 4; ++nt) {
                const bf16x8 wf = *(const bf16x8*)(W2t + (nt * 16 + mrow) * 64 + ks * 32 + quad * 8);
                acc[0][nt] = MFMA(a0, wf, acc[0][nt]);
                acc[1][nt] = MFMA(a1, wf, acc[1][nt]);
            }
        }
        #pragma unroll
        for (int mt = 0; mt < 2; ++mt)
            #pragma unroll
            for (int nt = 0; nt < 4; ++nt)
                #pragma unroll
                for (int r = 0; r < 4; ++r)
                    gbuf[(mt * 16 + quad * 4 + r) * 104 + nt * 16 + mrow] =
                        f2bf(fmaxf(acc[mt][nt][r], 0.0f));
    }

    // ============ layer 3: [32x64]x[64x128] two n-halves + maxpool ==========
    #pragma unroll
    for (int nh = 0; nh < 2; ++nh) {
        f32x4 acc[2][4];
        #pragma unroll
        for (int ntl = 0; ntl < 4; ++ntl) {
            const float bv = b3[(nh * 4 + ntl) * 16 + mrow];
            acc[0][ntl] = (f32x4){bv, bv, bv, bv};
            acc[1][ntl] = acc[0][ntl];
        }
        #pragma unroll
        for (int ks = 0; ks < 2; ++ks) {
            const bf16x8 a0 = *(const bf16x8*)(gbuf + mrow * 104 + ks * 32 + quad * 8);
            const bf16x8 a1 = *(const bf16x8*)(gbuf + (16 + mrow) * 104 + ks * 32 + quad * 8);
            #pragma unroll
            for (int ntl = 0; ntl < 4; ++ntl) {
                const bf16x8 wf = *(const bf16x8*)(
                    W3t + ((nh * 4 + ntl) * 16 + mrow) * 64 + ks * 32 + quad * 8);
                acc[0][ntl] = MFMA(a0, wf, acc[0][ntl]);
                acc[1][ntl] = MFMA(a1, wf, acc[1][ntl]);
            }
        }
        #pragma unroll
        for (int ntl = 0; ntl < 4; ++ntl) {
            const f32x4 v0 = acc[0][ntl], v1 = acc[1][ntl];
            float mx = fmaxf(fmaxf(v0[0], v0[1]), fmaxf(v0[2], v0[3]));
            mx = fmaxf(mx, fmaxf(fmaxf(v1[0], v1[1]), fmaxf(v1[2], v1[3])));
            mx = fmaxf(mx, __shfl_xor(mx, 16));
            mx = fmaxf(mx, __shfl_xor(mx, 32));
            mx = fmaxf(mx, 0.0f);
            if (quad == 0) stage[(nh * 4 + ntl) * 16 + mrow][w] = mx;
        }
    }
    __syncthreads();

    // ---- epilogue: 128 ch x 4 s, float2 per thread -------------------------
    {
        const int ch = threadIdx.x & 127;
        const int hf = threadIdx.x >> 7;           // 0/1
        float* dst = out_feat + ((size_t)b * 128 + ch) * SS + s0 + hf * 2;
        *(float2*)dst = make_float2(stage[ch][hf * 2], stage[ch][hf * 2 + 1]);
    }
}

// ---------------------------------------------------------------------------
extern "C" void kernel_launch(void* const* d_in, const int* in_sizes, int n_in,
                              void* d_out, int out_size, void* d_ws, size_t ws_size,
                              hipStream_t stream) {
    const float* xyz  = (const float*)d_in[0];
    const float* feat = (const float*)d_in[1];
    const float* W1   = (const float*)d_in[2];
    const float* b1   = (const float*)d_in[3];
    const float* W2   = (const float*)d_in[4];
    const float* b2   = (const float*)d_in[5];
    const float* W3   = (const float*)d_in[6];
    const float* b3   = (const float*)d_in[7];

    float* out      = (float*)d_out;
    float* out_xyz  = out;                               // [2,4096,3]
    float* out_feat = out + (size_t)BB * SS * 3;         // [2,128,4096]
    float* out_sidx = out_feat + (size_t)BB * 128 * SS;  // [2,4096]

    char* ws = (char*)d_ws;
    float4* pts4    = (float4*)(ws + WS_PTS4);
    ushort* feat_nc = (ushort*)(ws + WS_FEAT);
    ushort* W1t     = (ushort*)(ws + WS_W1T);
    ushort* W2t     = (ushort*)(ws + WS_W2T);
    ushort* W3t     = (ushort*)(ws + WS_W3T);

    prep_kernel<<<(T_ALL + 255) / 256, 256, 0, stream>>>(
        xyz, feat, W1, W2, W3, pts4, feat_nc, W1t, W2t, W3t, out_xyz, out_sidx);
    fused_kernel<<<BB * SS / 4, 256, 0, stream>>>(pts4, feat_nc, W1t, W2t, W3t,
                                                  b1, b2, b3, out_feat);
}